// Round 1
// baseline (400.101 us; speedup 1.0000x reference)
//
#include <hip/hip_runtime.h>

typedef unsigned short u16;
typedef __attribute__((ext_vector_type(8))) short bf16x8;
typedef __attribute__((ext_vector_type(4))) float f32x4;

#define HID 2048
#define NH 16
#define QLR 1536
#define KVLR 512
#define DR 64
#define DN 128
#define DQK 192
#define DV 128
#define SEQ 2048
#define NKVA 2176   // 1536 (q lora) + 576 (kv lora + rope) padded to 640 -> 2176 total

static __device__ __forceinline__ u16 f2bf(float f) {
  unsigned v = __builtin_bit_cast(unsigned, f);
  v = v + 0x7fffu + ((v >> 16) & 1u);
  return (u16)(v >> 16);
}
static __device__ __forceinline__ float bf2f(u16 u) {
  unsigned v = ((unsigned)u) << 16;
  return __builtin_bit_cast(float, v);
}

#define GLOAD16(gp, lp)                                                        \
  __builtin_amdgcn_global_load_lds(                                            \
      (const __attribute__((address_space(1))) void*)(gp),                     \
      (__attribute__((address_space(3))) void*)(lp), 16, 0, 0)

// ---------------- f32 -> bf16 convert; trailing region (i >= nsrc) zeroed ----
__global__ void k_convert(const float* __restrict__ src, u16* __restrict__ dst,
                          long nsrc, long ndst) {
  long i = ((long)blockIdx.x * blockDim.x + threadIdx.x) * 4;
  long stride = (long)gridDim.x * blockDim.x * 4;
  for (; i < ndst; i += stride) {
    u16 o0 = 0, o1 = 0, o2 = 0, o3 = 0;
    if (i < nsrc) {
      const float4 f = *(const float4*)(src + i);
      o0 = f2bf(f.x); o1 = f2bf(f.y); o2 = f2bf(f.z); o3 = f2bf(f.w);
    }
    u16* d = dst + i;
    d[0] = o0; d[1] = o1; d[2] = o2; d[3] = o3;
  }
}

// ---------------- row RMSNorm: Y[row][0..cols) = x*rsqrt(mean xx + eps)*w ----
__global__ void k_rmsnorm(const float* __restrict__ X, const float* __restrict__ w,
                          u16* __restrict__ Y, int xstride, int cols, float inv_cols) {
  const int row = blockIdx.x;
  const int t = threadIdx.x;
  const float* x = X + (size_t)row * xstride;
  float ss = 0.f;
  for (int i = t * 4; i < cols; i += 1024) {
    float4 v = *(const float4*)(x + i);
    ss += v.x * v.x + v.y * v.y + v.z * v.z + v.w * v.w;
  }
#pragma unroll
  for (int m = 1; m < 64; m <<= 1) ss += __shfl_xor(ss, m, 64);
  __shared__ float red[4];
  if ((t & 63) == 0) red[t >> 6] = ss;
  __syncthreads();
  float tot = red[0] + red[1] + red[2] + red[3];
  float r = rsqrtf(tot * inv_cols + 1e-6f);
  for (int i = t * 4; i < cols; i += 1024) {
    float4 v = *(const float4*)(x + i);
    float4 g = *(const float4*)(w + i);
    u16* y = Y + (size_t)row * cols + i;
    y[0] = f2bf(v.x * r * g.x);
    y[1] = f2bf(v.y * r * g.y);
    y[2] = f2bf(v.z * r * g.z);
    y[3] = f2bf(v.w * r * g.w);
  }
}

// ---------------- NT GEMM: C[M,N] = A[M,K] * B[N,K]^T, bf16 in, f32 acc -----
// 128x128 tile, BK=32, 4 waves each 64x64, global_load_lds staging (m97-style)
__global__ __launch_bounds__(256) void k_gemm_nt(
    const u16* __restrict__ A, const u16* __restrict__ B, void* __restrict__ Cout,
    int M, int N, int K, int c_bf16) {
  __shared__ __align__(16) u16 As[4096];
  __shared__ __align__(16) u16 Bs[4096];
  const int t = threadIdx.x;
  const int lane = t & 63;
  const int w = t >> 6, wr = w >> 1, wc = w & 1;
  const int lm = lane & 15, lg = lane >> 4;
  const int bm = blockIdx.y, bn = blockIdx.x;

  const u16* a0 = A + (size_t)(bm * 128 + (t >> 2)) * K + (t & 3) * 8;
  const u16* b0 = B + (size_t)(bn * 128 + (t >> 2)) * K + (t & 3) * 8;
  const size_t rK = (size_t)64 * K;
  u16* as0 = As + t * 8;
  u16* bs0 = Bs + t * 8;

  f32x4 acc[4][4] = {};
  for (int kt = 0; kt < K; kt += 32) {
    GLOAD16(a0 + kt, as0);
    GLOAD16(a0 + rK + kt, as0 + 2048);
    GLOAD16(b0 + kt, bs0);
    GLOAD16(b0 + rK + kt, bs0 + 2048);
    __syncthreads();  // implicit vmcnt(0) drain makes staging visible
    bf16x8 af[4], bfr[4];
#pragma unroll
    for (int i = 0; i < 4; ++i)
      af[i] = *(const bf16x8*)(As + (wr * 64 + i * 16 + lm) * 32 + lg * 8);
#pragma unroll
    for (int j = 0; j < 4; ++j)
      bfr[j] = *(const bf16x8*)(Bs + (wc * 64 + j * 16 + lm) * 32 + lg * 8);
#pragma unroll
    for (int i = 0; i < 4; ++i)
#pragma unroll
      for (int j = 0; j < 4; ++j)
        acc[i][j] = __builtin_amdgcn_mfma_f32_16x16x32_bf16(af[i], bfr[j], acc[i][j], 0, 0, 0);
    __syncthreads();  // protect LDS before next stage
  }
  const int row0 = bm * 128 + wr * 64 + lg * 4;
  const int col0 = bn * 128 + wc * 64 + lm;
  if (c_bf16) {
    u16* C = (u16*)Cout;
#pragma unroll
    for (int i = 0; i < 4; ++i)
#pragma unroll
      for (int r = 0; r < 4; ++r) {
        u16* crow = C + (size_t)(row0 + i * 16 + r) * N + col0;
#pragma unroll
        for (int j = 0; j < 4; ++j) crow[j * 16] = f2bf(acc[i][j][r]);
      }
  } else {
    float* C = (float*)Cout;
#pragma unroll
    for (int i = 0; i < 4; ++i)
#pragma unroll
      for (int r = 0; r < 4; ++r) {
        float* crow = C + (size_t)(row0 + i * 16 + r) * N + col0;
#pragma unroll
        for (int j = 0; j < 4; ++j) crow[j * 16] = acc[i][j][r];
      }
  }
}

// ---------------- assemble qf = [q_pass | rope(q_rot)] per head --------------
__global__ void k_mk_qf(const u16* __restrict__ qfull, const float* __restrict__ cosb,
                        const float* __restrict__ sinb, u16* __restrict__ qf) {
  const int s = blockIdx.x, h = blockIdx.y, t = threadIdx.x;
  const u16* src = qfull + (size_t)s * (NH * DQK) + h * DQK;
  u16* dst = qf + ((size_t)h * SEQ + s) * DQK;
  dst[t] = src[t];  // t < 128: pass dims (already bf16)
  if (t < 32) {
    float a = bf2f(src[DN + 2 * t]);
    float b = bf2f(src[DN + 2 * t + 1]);
    float c = cosb[(size_t)s * DR + t];
    float sn = sinb[(size_t)s * DR + t];
    dst[DN + t] = f2bf(a * c - b * sn);
    dst[DN + 32 + t] = f2bf(b * c + a * sn);
  }
}

// -------- assemble kf = [k_pass | rope(k_rot)] and v_t[h][d][s] --------------
__global__ void k_mk_kf_v(const u16* __restrict__ kvfull, const float* __restrict__ krot,
                          int krot_stride, const float* __restrict__ cosb,
                          const float* __restrict__ sinb, u16* __restrict__ kf,
                          u16* __restrict__ vt) {
  const int s = blockIdx.x, h = blockIdx.y, t = threadIdx.x;
  const u16* src = kvfull + (size_t)s * (NH * 256) + h * 256;
  u16* kdst = kf + ((size_t)h * SEQ + s) * DQK;
  kdst[t] = src[t];                                  // k_pass
  vt[((size_t)h * DV + t) * SEQ + s] = src[DN + t];  // transposed V
  if (t < 32) {
    float a = krot[(size_t)s * krot_stride + 2 * t];
    float b = krot[(size_t)s * krot_stride + 2 * t + 1];
    float c = cosb[(size_t)s * DR + t];
    float sn = sinb[(size_t)s * DR + t];
    kdst[DN + t] = f2bf(a * c - b * sn);
    kdst[DN + 32 + t] = f2bf(b * c + a * sn);
  }
}

// ---------------- flash attention, 2-segment causal --------------------------
// block = (head, 64-row q tile), 4 waves x 16 q rows
__global__ __launch_bounds__(256) void k_attn(
    const u16* __restrict__ qf, const u16* __restrict__ kf, const u16* __restrict__ vt,
    u16* __restrict__ attn_out, const int* __restrict__ cu, int ncu) {
  const int h = blockIdx.y;
  const int q0 = blockIdx.x * 64;
  const int t = threadIdx.x, lane = t & 63, w = t >> 6;
  const int lm = lane & 15, lg = lane >> 4;
  const float SCALE = 0.07216878364870323f;  // 192^-0.5

  // Q fragments (A-frag: row = q0 + w*16 + lm, k chunk at lg*8)
  bf16x8 qfr[6];
  {
    const u16* qp = qf + ((size_t)h * SEQ + (q0 + w * 16 + lm)) * DQK + lg * 8;
#pragma unroll
    for (int c = 0; c < 6; ++c) qfr[c] = *(const bf16x8*)(qp + c * 32);
  }

  // D-layout rows this lane owns + their segment starts
  int qrow[4], segs[4];
#pragma unroll
  for (int r = 0; r < 4; ++r) {
    qrow[r] = q0 + w * 16 + lg * 4 + r;
    int ss = 0;
    for (int j = 0; j < ncu; ++j)
      if (cu[j] <= qrow[r]) ss = cu[j];
    segs[r] = ss;
  }
  int s_lo = 0, s_hi = 0;
  for (int j = 0; j < ncu; ++j) {
    if (cu[j] <= q0) s_lo = cu[j];
    if (cu[j] <= q0 + 63) s_hi = cu[j];
  }
  const int kt_start = (s_lo == s_hi) ? (s_lo >> 6) : 0;
  const int kt_end = q0 >> 6;

  float m_r[4], l_r[4];
#pragma unroll
  for (int r = 0; r < 4; ++r) { m_r[r] = -1e30f; l_r[r] = 0.f; }
  f32x4 oacc[8] = {};

  __shared__ __align__(16) u16 p_lds[4][16][64];

  for (int kt = kt_start; kt <= kt_end; ++kt) {
    const int k0 = kt * 64;
    f32x4 sc[4] = {};
    const u16* kbase = kf + ((size_t)h * SEQ + (k0 + lm)) * DQK + lg * 8;
#pragma unroll
    for (int n0 = 0; n0 < 4; ++n0) {
      const u16* kp = kbase + (size_t)n0 * 16 * DQK;
#pragma unroll
      for (int c = 0; c < 6; ++c) {
        bf16x8 kfr = *(const bf16x8*)(kp + c * 32);
        sc[n0] = __builtin_amdgcn_mfma_f32_16x16x32_bf16(qfr[c], kfr, sc[n0], 0, 0, 0);
      }
    }
    // online softmax update (rows owned: lg*4 + r; cols: k0 + n0*16 + lm)
#pragma unroll
    for (int r = 0; r < 4; ++r) {
      float scr[4];
#pragma unroll
      for (int n0 = 0; n0 < 4; ++n0) {
        int kc = k0 + n0 * 16 + lm;
        bool valid = (kc >= segs[r]) && (kc <= qrow[r]);
        scr[n0] = valid ? sc[n0][r] * SCALE : -1e30f;
      }
      float mx = fmaxf(fmaxf(scr[0], scr[1]), fmaxf(scr[2], scr[3]));
#pragma unroll
      for (int md = 1; md < 16; md <<= 1) mx = fmaxf(mx, __shfl_xor(mx, md, 64));
      float mnew = fmaxf(m_r[r], mx);
      float alpha = __expf(m_r[r] - mnew);
      float p[4], ps = 0.f;
#pragma unroll
      for (int n0 = 0; n0 < 4; ++n0) { p[n0] = __expf(scr[n0] - mnew); ps += p[n0]; }
#pragma unroll
      for (int md = 1; md < 16; md <<= 1) ps += __shfl_xor(ps, md, 64);
      l_r[r] = l_r[r] * alpha + ps;
      m_r[r] = mnew;
#pragma unroll
      for (int nd = 0; nd < 8; ++nd) oacc[nd][r] *= alpha;
      const int prow = lg * 4 + r;
#pragma unroll
      for (int n0 = 0; n0 < 4; ++n0) p_lds[w][prow][n0 * 16 + lm] = f2bf(p[n0]);
    }
    asm volatile("s_waitcnt lgkmcnt(0)" ::: "memory");  // wave-local P transpose
    bf16x8 pa0 = *(const bf16x8*)(&p_lds[w][lm][lg * 8]);
    bf16x8 pa1 = *(const bf16x8*)(&p_lds[w][lm][32 + lg * 8]);
    const u16* vbase = vt + ((size_t)h * DV + lm) * SEQ + k0 + lg * 8;
#pragma unroll
    for (int nd = 0; nd < 8; ++nd) {
      const u16* vp = vbase + (size_t)nd * 16 * SEQ;
      bf16x8 v0 = *(const bf16x8*)(vp);
      bf16x8 v1 = *(const bf16x8*)(vp + 32);
      oacc[nd] = __builtin_amdgcn_mfma_f32_16x16x32_bf16(pa0, v0, oacc[nd], 0, 0, 0);
      oacc[nd] = __builtin_amdgcn_mfma_f32_16x16x32_bf16(pa1, v1, oacc[nd], 0, 0, 0);
    }
  }
#pragma unroll
  for (int r = 0; r < 4; ++r) {
    float inv = 1.0f / l_r[r];
#pragma unroll
    for (int nd = 0; nd < 8; ++nd)
      attn_out[(size_t)qrow[r] * (NH * DV) + h * DV + nd * 16 + lm] = f2bf(oacc[nd][r] * inv);
  }
}

extern "C" void kernel_launch(void* const* d_in, const int* in_sizes, int n_in,
                              void* d_out, int out_size, void* d_ws, size_t ws_size,
                              hipStream_t stream) {
  const float* hs = (const float*)d_in[0];
  const float* cosb = (const float*)d_in[1];
  const float* sinb = (const float*)d_in[2];
  const float* wq_a = (const float*)d_in[3];
  const float* q_a_ln_w = (const float*)d_in[4];
  const float* wq_b = (const float*)d_in[5];
  const float* wkv_a = (const float*)d_in[6];
  const float* kv_a_ln_w = (const float*)d_in[7];
  const float* wkv_b = (const float*)d_in[8];
  const float* wo = (const float*)d_in[9];
  const int* cu = (const int*)d_in[10];
  const int ncu = in_sizes[10];

  char* ws = (char*)d_ws;
  size_t off = 0;
  auto take = [&](size_t bytes) {
    size_t o = off;
    off += (bytes + 255) & ~(size_t)255;
    return o;
  };
  u16* hs_bf = (u16*)(ws + take((size_t)SEQ * HID * 2));
  u16* wqkva = (u16*)(ws + take((size_t)NKVA * HID * 2));       // [wq_a;wkv_a(pad 640)]
  u16* wqb = (u16*)(ws + take((size_t)(NH * DQK) * QLR * 2));
  u16* wkvb = (u16*)(ws + take((size_t)(NH * 256) * KVLR * 2));
  u16* wo_bf = (u16*)(ws + take((size_t)HID * (NH * DV) * 2));
  float* qkva = (float*)(ws + take((size_t)SEQ * NKVA * 4));    // q_a | kv_c | k_rot | pad
  u16* q_ln = (u16*)(ws + take((size_t)SEQ * QLR * 2));
  u16* kv_ln = (u16*)(ws + take((size_t)SEQ * KVLR * 2));
  u16* qfull = (u16*)(ws + take((size_t)SEQ * NH * DQK * 2));
  u16* kvfull = (u16*)(ws + take((size_t)SEQ * NH * 256 * 2));
  u16* qf = (u16*)(ws + take((size_t)NH * SEQ * DQK * 2));
  u16* kf = (u16*)(ws + take((size_t)NH * SEQ * DQK * 2));
  u16* vt = (u16*)(ws + take((size_t)NH * DV * SEQ * 2));
  u16* attn = (u16*)(ws + take((size_t)SEQ * NH * DV * 2));
  if (off > ws_size) return;

  auto blocks4 = [](long n) {
    long b = (n / 4 + 255) / 256;
    return (int)(b > 4096 ? 4096 : b);
  };

  // converts (f32 -> bf16), wkv_a zero-padded 576 -> 640 rows
  k_convert<<<blocks4((long)SEQ * HID), 256, 0, stream>>>(hs, hs_bf, (long)SEQ * HID, (long)SEQ * HID);
  k_convert<<<blocks4((long)QLR * HID), 256, 0, stream>>>(wq_a, wqkva, (long)QLR * HID, (long)QLR * HID);
  k_convert<<<blocks4((long)640 * HID), 256, 0, stream>>>(wkv_a, wqkva + (size_t)QLR * HID,
                                                          (long)(KVLR + DR) * HID, (long)640 * HID);
  k_convert<<<blocks4((long)NH * DQK * QLR), 256, 0, stream>>>(wq_b, wqb, (long)NH * DQK * QLR,
                                                               (long)NH * DQK * QLR);
  k_convert<<<blocks4((long)NH * 256 * KVLR), 256, 0, stream>>>(wkv_b, wkvb, (long)NH * 256 * KVLR,
                                                                (long)NH * 256 * KVLR);
  k_convert<<<blocks4((long)HID * NH * DV), 256, 0, stream>>>(wo, wo_bf, (long)HID * NH * DV,
                                                              (long)HID * NH * DV);

  // fused low-rank down-proj: [q_a | ckv] = hs @ [wq_a;wkv_a]^T
  dim3 g1(NKVA / 128, SEQ / 128);
  k_gemm_nt<<<g1, 256, 0, stream>>>(hs_bf, wqkva, qkva, SEQ, NKVA, HID, 0);

  k_rmsnorm<<<SEQ, 256, 0, stream>>>(qkva, q_a_ln_w, q_ln, NKVA, QLR, 1.0f / QLR);
  k_rmsnorm<<<SEQ, 256, 0, stream>>>(qkva + QLR, kv_a_ln_w, kv_ln, NKVA, KVLR, 1.0f / KVLR);

  dim3 g2(NH * DQK / 128, SEQ / 128);
  k_gemm_nt<<<g2, 256, 0, stream>>>(q_ln, wqb, qfull, SEQ, NH * DQK, QLR, 1);
  dim3 g3(NH * 256 / 128, SEQ / 128);
  k_gemm_nt<<<g3, 256, 0, stream>>>(kv_ln, wkvb, kvfull, SEQ, NH * 256, KVLR, 1);

  k_mk_qf<<<dim3(SEQ, NH), 128, 0, stream>>>(qfull, cosb, sinb, qf);
  k_mk_kf_v<<<dim3(SEQ, NH), 128, 0, stream>>>(kvfull, qkva + (QLR + KVLR), NKVA, cosb, sinb, kf, vt);

  k_attn<<<dim3(SEQ / 64, NH), 256, 0, stream>>>(qf, kf, vt, attn, cu, ncu);

  dim3 g4(HID / 128, SEQ / 128);
  k_gemm_nt<<<g4, 256, 0, stream>>>(attn, wo_bf, d_out, SEQ, HID, NH * DV, 0);
}

// Round 2
// 316.200 us; speedup vs baseline: 1.2653x; 1.2653x over previous
//
#include <hip/hip_runtime.h>

typedef unsigned short u16;
typedef __attribute__((ext_vector_type(8))) short bf16x8;
typedef __attribute__((ext_vector_type(4))) float f32x4;

#define HID 2048
#define NH 16
#define QLR 1536
#define KVLR 512
#define DR 64
#define DN 128
#define DQK 192
#define DV 128
#define SEQ 2048
#define NKVA 2176   // 1536 (q lora) + 576 (kv lora + rope) padded to 640 -> 2176 total

static __device__ __forceinline__ u16 f2bf(float f) {
  unsigned v = __builtin_bit_cast(unsigned, f);
  v = v + 0x7fffu + ((v >> 16) & 1u);
  return (u16)(v >> 16);
}
static __device__ __forceinline__ float bf2f(u16 u) {
  unsigned v = ((unsigned)u) << 16;
  return __builtin_bit_cast(float, v);
}

#define GLOAD16(gp, lp)                                                        \
  __builtin_amdgcn_global_load_lds(                                            \
      (const __attribute__((address_space(1))) void*)(gp),                     \
      (__attribute__((address_space(3))) void*)(lp), 16, 0, 0)

// ---------------- f32 -> bf16 convert; trailing region (i >= nsrc) zeroed ----
__global__ void k_convert(const float* __restrict__ src, u16* __restrict__ dst,
                          long nsrc, long ndst) {
  long i = ((long)blockIdx.x * blockDim.x + threadIdx.x) * 4;
  long stride = (long)gridDim.x * blockDim.x * 4;
  for (; i < ndst; i += stride) {
    u16 o0 = 0, o1 = 0, o2 = 0, o3 = 0;
    if (i < nsrc) {
      const float4 f = *(const float4*)(src + i);
      o0 = f2bf(f.x); o1 = f2bf(f.y); o2 = f2bf(f.z); o3 = f2bf(f.w);
    }
    u16* d = dst + i;
    d[0] = o0; d[1] = o1; d[2] = o2; d[3] = o3;
  }
}

// ---------------- row RMSNorm: Y[row][0..cols) = x*rsqrt(mean xx + eps)*w ----
__global__ void k_rmsnorm(const float* __restrict__ X, const float* __restrict__ w,
                          u16* __restrict__ Y, int xstride, int cols, float inv_cols) {
  const int row = blockIdx.x;
  const int t = threadIdx.x;
  const float* x = X + (size_t)row * xstride;
  float ss = 0.f;
  for (int i = t * 4; i < cols; i += 1024) {
    float4 v = *(const float4*)(x + i);
    ss += v.x * v.x + v.y * v.y + v.z * v.z + v.w * v.w;
  }
#pragma unroll
  for (int m = 1; m < 64; m <<= 1) ss += __shfl_xor(ss, m, 64);
  __shared__ float red[4];
  if ((t & 63) == 0) red[t >> 6] = ss;
  __syncthreads();
  float tot = red[0] + red[1] + red[2] + red[3];
  float r = rsqrtf(tot * inv_cols + 1e-6f);
  for (int i = t * 4; i < cols; i += 1024) {
    float4 v = *(const float4*)(x + i);
    float4 g = *(const float4*)(w + i);
    u16* y = Y + (size_t)row * cols + i;
    y[0] = f2bf(v.x * r * g.x);
    y[1] = f2bf(v.y * r * g.y);
    y[2] = f2bf(v.z * r * g.z);
    y[3] = f2bf(v.w * r * g.w);
  }
}

// ---------------- NT GEMM: C[M,N] = A[M,K] * B[N,K]^T, bf16 in, f32 acc -----
// 128x128 tile, BK=32, 4 waves each 64x64, global_load_lds staging (m97-style)
__global__ __launch_bounds__(256) void k_gemm_nt(
    const u16* __restrict__ A, const u16* __restrict__ B, void* __restrict__ Cout,
    int M, int N, int K, int c_bf16) {
  __shared__ __align__(16) u16 As[4096];
  __shared__ __align__(16) u16 Bs[4096];
  const int t = threadIdx.x;
  const int lane = t & 63;
  const int w = t >> 6, wr = w >> 1, wc = w & 1;
  const int lm = lane & 15, lg = lane >> 4;
  const int bm = blockIdx.y, bn = blockIdx.x;

  const u16* a0 = A + (size_t)(bm * 128 + (t >> 2)) * K + (t & 3) * 8;
  const u16* b0 = B + (size_t)(bn * 128 + (t >> 2)) * K + (t & 3) * 8;
  const size_t rK = (size_t)64 * K;
  u16* as0 = As + t * 8;
  u16* bs0 = Bs + t * 8;

  f32x4 acc[4][4] = {};
  for (int kt = 0; kt < K; kt += 32) {
    GLOAD16(a0 + kt, as0);
    GLOAD16(a0 + rK + kt, as0 + 2048);
    GLOAD16(b0 + kt, bs0);
    GLOAD16(b0 + rK + kt, bs0 + 2048);
    __syncthreads();  // implicit vmcnt(0) drain makes staging visible
    bf16x8 af[4], bfr[4];
#pragma unroll
    for (int i = 0; i < 4; ++i)
      af[i] = *(const bf16x8*)(As + (wr * 64 + i * 16 + lm) * 32 + lg * 8);
#pragma unroll
    for (int j = 0; j < 4; ++j)
      bfr[j] = *(const bf16x8*)(Bs + (wc * 64 + j * 16 + lm) * 32 + lg * 8);
#pragma unroll
    for (int i = 0; i < 4; ++i)
#pragma unroll
      for (int j = 0; j < 4; ++j)
        acc[i][j] = __builtin_amdgcn_mfma_f32_16x16x32_bf16(af[i], bfr[j], acc[i][j], 0, 0, 0);
    __syncthreads();  // protect LDS before next stage
  }
  const int row0 = bm * 128 + wr * 64 + lg * 4;
  const int col0 = bn * 128 + wc * 64 + lm;
  if (c_bf16) {
    u16* C = (u16*)Cout;
#pragma unroll
    for (int i = 0; i < 4; ++i)
#pragma unroll
      for (int r = 0; r < 4; ++r) {
        u16* crow = C + (size_t)(row0 + i * 16 + r) * N + col0;
#pragma unroll
        for (int j = 0; j < 4; ++j) crow[j * 16] = f2bf(acc[i][j][r]);
      }
  } else {
    float* C = (float*)Cout;
#pragma unroll
    for (int i = 0; i < 4; ++i)
#pragma unroll
      for (int r = 0; r < 4; ++r) {
        float* crow = C + (size_t)(row0 + i * 16 + r) * N + col0;
#pragma unroll
        for (int j = 0; j < 4; ++j) crow[j * 16] = acc[i][j][r];
      }
  }
}

// ---------------- assemble qf = [q_pass | rope(q_rot)] per head --------------
__global__ void k_mk_qf(const u16* __restrict__ qfull, const float* __restrict__ cosb,
                        const float* __restrict__ sinb, u16* __restrict__ qf) {
  const int s = blockIdx.x, h = blockIdx.y, t = threadIdx.x;
  const u16* src = qfull + (size_t)s * (NH * DQK) + h * DQK;
  u16* dst = qf + ((size_t)h * SEQ + s) * DQK;
  dst[t] = src[t];  // t < 128: pass dims (already bf16)
  if (t < 32) {
    float a = bf2f(src[DN + 2 * t]);
    float b = bf2f(src[DN + 2 * t + 1]);
    float c = cosb[(size_t)s * DR + t];
    float sn = sinb[(size_t)s * DR + t];
    dst[DN + t] = f2bf(a * c - b * sn);
    dst[DN + 32 + t] = f2bf(b * c + a * sn);
  }
}

// -------- assemble kf = [k_pass | rope(k_rot)] and v_t[h][d][s] --------------
__global__ void k_mk_kf_v(const u16* __restrict__ kvfull, const float* __restrict__ krot,
                          int krot_stride, const float* __restrict__ cosb,
                          const float* __restrict__ sinb, u16* __restrict__ kf,
                          u16* __restrict__ vt) {
  const int s = blockIdx.x, h = blockIdx.y, t = threadIdx.x;
  const u16* src = kvfull + (size_t)s * (NH * 256) + h * 256;
  u16* kdst = kf + ((size_t)h * SEQ + s) * DQK;
  kdst[t] = src[t];                                  // k_pass
  vt[((size_t)h * DV + t) * SEQ + s] = src[DN + t];  // transposed V
  if (t < 32) {
    float a = krot[(size_t)s * krot_stride + 2 * t];
    float b = krot[(size_t)s * krot_stride + 2 * t + 1];
    float c = cosb[(size_t)s * DR + t];
    float sn = sinb[(size_t)s * DR + t];
    kdst[DN + t] = f2bf(a * c - b * sn);
    kdst[DN + 32 + t] = f2bf(b * c + a * sn);
  }
}

// ---------------- flash attention v2: independent 16-row waves ---------------
// grid: 512 blocks x 256 thr; 4 free-running waves/block, no barriers.
// wave -> (head, 16-row q tile); head pinned to XCD via bid%8; reversed q
// order so longest waves dispatch first. KVBLK=32, register double-buffered
// K prefetch (kA/kB), V single-buffered (latency hidden under QK+softmax).
__global__ __launch_bounds__(256) void k_attn(
    const u16* __restrict__ qf, const u16* __restrict__ kf, const u16* __restrict__ vt,
    u16* __restrict__ attn_out, const int* __restrict__ cu, int ncu) {
  const int bid = blockIdx.x;
  const int t = threadIdx.x, lane = t & 63, w = t >> 6;
  const int lm = lane & 15, lg = lane >> 4;
  const int x = bid & 7, j = bid >> 3;
  const int h = x * 2 + (j & 1);           // 2 heads per XCD -> K/V L2-resident
  const int qi = 127 - ((j >> 1) * 4 + w); // reversed: longest first
  const float SCALE = 0.07216878364870323f;  // 192^-0.5

  // Q fragments: A-frag row = lm (q row qi*16+lm), k chunk lg*8 + c*32
  bf16x8 qfr[6];
  {
    const u16* qp = qf + ((size_t)h * SEQ + (qi * 16 + lm)) * DQK + lg * 8;
#pragma unroll
    for (int c = 0; c < 6; ++c) qfr[c] = *(const bf16x8*)(qp + c * 32);
  }

  const int lo_row = qi * 16;
  int s_lo = 0;
  for (int jj = 0; jj < ncu; ++jj)
    if (cu[jj] <= lo_row) s_lo = cu[jj];
  int qrow[4], segs[4];
#pragma unroll
  for (int r = 0; r < 4; ++r) {
    qrow[r] = lo_row + lg * 4 + r;
    int ss = 0;
    for (int jj = 0; jj < ncu; ++jj)
      if (cu[jj] <= qrow[r]) ss = cu[jj];
    segs[r] = ss;
  }
  const int kt_start = s_lo >> 5;
  const int kt_end = (lo_row + 15) >> 5;

  float m_r[4], l_r[4];
#pragma unroll
  for (int r = 0; r < 4; ++r) { m_r[r] = -1e30f; l_r[r] = 0.f; }
  f32x4 oacc[8] = {};

  __shared__ __align__(16) u16 p_lds[4][16][32];

  bf16x8 kA[12], kB[12], vv[8];

#define LOADK(kreg, kt)                                                        \
  do {                                                                         \
    const u16* kp_ = kf + ((size_t)h * SEQ + (kt) * 32 + lm) * DQK + lg * 8;   \
    _Pragma("unroll") for (int n0_ = 0; n0_ < 2; ++n0_)                        \
        _Pragma("unroll") for (int c_ = 0; c_ < 6; ++c_)                       \
            kreg[n0_ * 6 + c_] =                                               \
        *(const bf16x8*)(kp_ + (size_t)n0_ * 16 * DQK + c_ * 32);              \
  } while (0)

#define LOADV(kt)                                                              \
  do {                                                                         \
    const u16* vp_ = vt + ((size_t)h * DV + lm) * SEQ + (kt) * 32 + lg * 8;    \
    _Pragma("unroll") for (int nd_ = 0; nd_ < 8; ++nd_)                        \
        vv[nd_] = *(const bf16x8*)(vp_ + (size_t)nd_ * 16 * SEQ);              \
  } while (0)

#define COMPUTE(kreg, kt)                                                      \
  do {                                                                         \
    const int k0_ = (kt) * 32;                                                 \
    f32x4 sc[2] = {};                                                          \
    _Pragma("unroll") for (int n0_ = 0; n0_ < 2; ++n0_)                        \
        _Pragma("unroll") for (int c_ = 0; c_ < 6; ++c_)                       \
            sc[n0_] = __builtin_amdgcn_mfma_f32_16x16x32_bf16(                 \
        qfr[c_], kreg[n0_ * 6 + c_], sc[n0_], 0, 0, 0);                        \
    _Pragma("unroll") for (int r = 0; r < 4; ++r) {                            \
      float s0, s1;                                                            \
      {                                                                        \
        int kc0 = k0_ + lm, kc1 = k0_ + 16 + lm;                               \
        s0 = (kc0 >= segs[r] && kc0 <= qrow[r]) ? sc[0][r] * SCALE : -1e30f;   \
        s1 = (kc1 >= segs[r] && kc1 <= qrow[r]) ? sc[1][r] * SCALE : -1e30f;   \
      }                                                                        \
      float mx = fmaxf(s0, s1);                                                \
      _Pragma("unroll") for (int md = 1; md < 16; md <<= 1)                    \
          mx = fmaxf(mx, __shfl_xor(mx, md, 64));                              \
      float mnew = fmaxf(m_r[r], mx);                                          \
      float alpha = __expf(m_r[r] - mnew);                                     \
      float p0 = __expf(s0 - mnew), p1 = __expf(s1 - mnew);                    \
      float ps = p0 + p1;                                                      \
      _Pragma("unroll") for (int md = 1; md < 16; md <<= 1)                    \
          ps += __shfl_xor(ps, md, 64);                                        \
      l_r[r] = l_r[r] * alpha + ps;                                            \
      m_r[r] = mnew;                                                           \
      _Pragma("unroll") for (int nd = 0; nd < 8; ++nd) oacc[nd][r] *= alpha;   \
      const int prow = lg * 4 + r;                                             \
      p_lds[w][prow][lm] = f2bf(p0);                                           \
      p_lds[w][prow][16 + lm] = f2bf(p1);                                      \
    }                                                                          \
    asm volatile("s_waitcnt lgkmcnt(0)" ::: "memory");                         \
    __builtin_amdgcn_sched_barrier(0);                                         \
    bf16x8 pa = *(const bf16x8*)(&p_lds[w][lm][lg * 8]);                       \
    _Pragma("unroll") for (int nd = 0; nd < 8; ++nd)                           \
        oacc[nd] =                                                             \
        __builtin_amdgcn_mfma_f32_16x16x32_bf16(pa, vv[nd], oacc[nd], 0, 0, 0);\
  } while (0)

  int kt = kt_start;
  LOADK(kA, kt);
  for (;;) {
    if (kt + 1 <= kt_end) LOADK(kB, kt + 1);
    LOADV(kt);
    COMPUTE(kA, kt);
    ++kt;
    if (kt > kt_end) break;
    if (kt + 1 <= kt_end) LOADK(kA, kt + 1);
    LOADV(kt);
    COMPUTE(kB, kt);
    ++kt;
    if (kt > kt_end) break;
  }
#undef LOADK
#undef LOADV
#undef COMPUTE

#pragma unroll
  for (int r = 0; r < 4; ++r) {
    float inv = 1.0f / l_r[r];
#pragma unroll
    for (int nd = 0; nd < 8; ++nd)
      attn_out[(size_t)qrow[r] * (NH * DV) + h * DV + nd * 16 + lm] =
          f2bf(oacc[nd][r] * inv);
  }
}

extern "C" void kernel_launch(void* const* d_in, const int* in_sizes, int n_in,
                              void* d_out, int out_size, void* d_ws, size_t ws_size,
                              hipStream_t stream) {
  const float* hs = (const float*)d_in[0];
  const float* cosb = (const float*)d_in[1];
  const float* sinb = (const float*)d_in[2];
  const float* wq_a = (const float*)d_in[3];
  const float* q_a_ln_w = (const float*)d_in[4];
  const float* wq_b = (const float*)d_in[5];
  const float* wkv_a = (const float*)d_in[6];
  const float* kv_a_ln_w = (const float*)d_in[7];
  const float* wkv_b = (const float*)d_in[8];
  const float* wo = (const float*)d_in[9];
  const int* cu = (const int*)d_in[10];
  const int ncu = in_sizes[10];

  char* ws = (char*)d_ws;
  size_t off = 0;
  auto take = [&](size_t bytes) {
    size_t o = off;
    off += (bytes + 255) & ~(size_t)255;
    return o;
  };
  u16* hs_bf = (u16*)(ws + take((size_t)SEQ * HID * 2));
  u16* wqkva = (u16*)(ws + take((size_t)NKVA * HID * 2));       // [wq_a;wkv_a(pad 640)]
  u16* wqb = (u16*)(ws + take((size_t)(NH * DQK) * QLR * 2));
  u16* wkvb = (u16*)(ws + take((size_t)(NH * 256) * KVLR * 2));
  u16* wo_bf = (u16*)(ws + take((size_t)HID * (NH * DV) * 2));
  float* qkva = (float*)(ws + take((size_t)SEQ * NKVA * 4));    // q_a | kv_c | k_rot | pad
  u16* q_ln = (u16*)(ws + take((size_t)SEQ * QLR * 2));
  u16* kv_ln = (u16*)(ws + take((size_t)SEQ * KVLR * 2));
  u16* qfull = (u16*)(ws + take((size_t)SEQ * NH * DQK * 2));
  u16* kvfull = (u16*)(ws + take((size_t)SEQ * NH * 256 * 2));
  u16* qf = (u16*)(ws + take((size_t)NH * SEQ * DQK * 2));
  u16* kf = (u16*)(ws + take((size_t)NH * SEQ * DQK * 2));
  u16* vt = (u16*)(ws + take((size_t)NH * DV * SEQ * 2));
  u16* attn = (u16*)(ws + take((size_t)SEQ * NH * DV * 2));
  if (off > ws_size) return;

  auto blocks4 = [](long n) {
    long b = (n / 4 + 255) / 256;
    return (int)(b > 4096 ? 4096 : b);
  };

  // converts (f32 -> bf16), wkv_a zero-padded 576 -> 640 rows
  k_convert<<<blocks4((long)SEQ * HID), 256, 0, stream>>>(hs, hs_bf, (long)SEQ * HID, (long)SEQ * HID);
  k_convert<<<blocks4((long)QLR * HID), 256, 0, stream>>>(wq_a, wqkva, (long)QLR * HID, (long)QLR * HID);
  k_convert<<<blocks4((long)640 * HID), 256, 0, stream>>>(wkv_a, wqkva + (size_t)QLR * HID,
                                                          (long)(KVLR + DR) * HID, (long)640 * HID);
  k_convert<<<blocks4((long)NH * DQK * QLR), 256, 0, stream>>>(wq_b, wqb, (long)NH * DQK * QLR,
                                                               (long)NH * DQK * QLR);
  k_convert<<<blocks4((long)NH * 256 * KVLR), 256, 0, stream>>>(wkv_b, wkvb, (long)NH * 256 * KVLR,
                                                                (long)NH * 256 * KVLR);
  k_convert<<<blocks4((long)HID * NH * DV), 256, 0, stream>>>(wo, wo_bf, (long)HID * NH * DV,
                                                              (long)HID * NH * DV);

  // fused low-rank down-proj: [q_a | ckv] = hs @ [wq_a;wkv_a]^T
  dim3 g1(NKVA / 128, SEQ / 128);
  k_gemm_nt<<<g1, 256, 0, stream>>>(hs_bf, wqkva, qkva, SEQ, NKVA, HID, 0);

  k_rmsnorm<<<SEQ, 256, 0, stream>>>(qkva, q_a_ln_w, q_ln, NKVA, QLR, 1.0f / QLR);
  k_rmsnorm<<<SEQ, 256, 0, stream>>>(qkva + QLR, kv_a_ln_w, kv_ln, NKVA, KVLR, 1.0f / KVLR);

  dim3 g2(NH * DQK / 128, SEQ / 128);
  k_gemm_nt<<<g2, 256, 0, stream>>>(q_ln, wqb, qfull, SEQ, NH * DQK, QLR, 1);
  dim3 g3(NH * 256 / 128, SEQ / 128);
  k_gemm_nt<<<g3, 256, 0, stream>>>(kv_ln, wkvb, kvfull, SEQ, NH * 256, KVLR, 1);

  k_mk_qf<<<dim3(SEQ, NH), 128, 0, stream>>>(qfull, cosb, sinb, qf);
  k_mk_kf_v<<<dim3(SEQ, NH), 128, 0, stream>>>(kvfull, qkva + (QLR + KVLR), NKVA, cosb, sinb, kf, vt);

  k_attn<<<512, 256, 0, stream>>>(qf, kf, vt, attn, cu, ncu);

  dim3 g4(HID / 128, SEQ / 128);
  k_gemm_nt<<<g4, 256, 0, stream>>>(attn, wo_bf, d_out, SEQ, HID, NH * DV, 0);
}

// Round 3
// 307.056 us; speedup vs baseline: 1.3030x; 1.0298x over previous
//
#include <hip/hip_runtime.h>

typedef unsigned short u16;
typedef __attribute__((ext_vector_type(8))) short bf16x8;
typedef __attribute__((ext_vector_type(4))) float f32x4;

#define HID 2048
#define NH 16
#define QLR 1536
#define KVLR 512
#define DR 64
#define DN 128
#define DQK 192
#define DV 128
#define SEQ 2048
#define NKVA 2176   // 1536 (q lora) + 576 (kv lora + rope) padded to 640 -> 2176 total
#define SCALE 0.07216878364870323f  // 192^-0.5

static __device__ __forceinline__ u16 f2bf(float f) {
  unsigned v = __builtin_bit_cast(unsigned, f);
  v = v + 0x7fffu + ((v >> 16) & 1u);
  return (u16)(v >> 16);
}
static __device__ __forceinline__ float bf2f(u16 u) {
  unsigned v = ((unsigned)u) << 16;
  return __builtin_bit_cast(float, v);
}

#define GLOAD16(gp, lp)                                                        \
  __builtin_amdgcn_global_load_lds(                                            \
      (const __attribute__((address_space(1))) void*)(gp),                     \
      (__attribute__((address_space(3))) void*)(lp), 16, 0, 0)

// ---------------- f32 -> bf16 convert; trailing region (i >= nsrc) zeroed ----
__global__ void k_convert(const float* __restrict__ src, u16* __restrict__ dst,
                          long nsrc, long ndst) {
  long i = ((long)blockIdx.x * blockDim.x + threadIdx.x) * 4;
  long stride = (long)gridDim.x * blockDim.x * 4;
  for (; i < ndst; i += stride) {
    u16 o0 = 0, o1 = 0, o2 = 0, o3 = 0;
    if (i < nsrc) {
      const float4 f = *(const float4*)(src + i);
      o0 = f2bf(f.x); o1 = f2bf(f.y); o2 = f2bf(f.z); o3 = f2bf(f.w);
    }
    u16* d = dst + i;
    d[0] = o0; d[1] = o1; d[2] = o2; d[3] = o3;
  }
}

// ---------------- row RMSNorm: Y[row][0..cols) = x*rsqrt(mean xx + eps)*w ----
__global__ void k_rmsnorm(const float* __restrict__ X, const float* __restrict__ w,
                          u16* __restrict__ Y, int xstride, int cols, float inv_cols) {
  const int row = blockIdx.x;
  const int t = threadIdx.x;
  const float* x = X + (size_t)row * xstride;
  float ss = 0.f;
  for (int i = t * 4; i < cols; i += 1024) {
    float4 v = *(const float4*)(x + i);
    ss += v.x * v.x + v.y * v.y + v.z * v.z + v.w * v.w;
  }
#pragma unroll
  for (int m = 1; m < 64; m <<= 1) ss += __shfl_xor(ss, m, 64);
  __shared__ float red[4];
  if ((t & 63) == 0) red[t >> 6] = ss;
  __syncthreads();
  float tot = red[0] + red[1] + red[2] + red[3];
  float r = rsqrtf(tot * inv_cols + 1e-6f);
  for (int i = t * 4; i < cols; i += 1024) {
    float4 v = *(const float4*)(x + i);
    float4 g = *(const float4*)(w + i);
    u16* y = Y + (size_t)row * cols + i;
    y[0] = f2bf(v.x * r * g.x);
    y[1] = f2bf(v.y * r * g.y);
    y[2] = f2bf(v.z * r * g.z);
    y[3] = f2bf(v.w * r * g.w);
  }
}

// ---------------- NT GEMM: C[M,N] = A[M,K] * B[N,K]^T, bf16 in, f32 acc -----
// 128x128 tile, BK=32, 4 waves each 64x64, global_load_lds staging (m97-style)
// + bijective XCD swizzle, column-major within XCD (B panel L2-resident)
__global__ __launch_bounds__(256) void k_gemm_nt(
    const u16* __restrict__ A, const u16* __restrict__ B, void* __restrict__ Cout,
    int M, int N, int K, int c_bf16) {
  __shared__ __align__(16) u16 As[4096];
  __shared__ __align__(16) u16 Bs[4096];
  const int t = threadIdx.x;
  const int lane = t & 63;
  const int w = t >> 6, wr = w >> 1, wc = w & 1;
  const int lm = lane & 15, lg = lane >> 4;

  const int nwg = gridDim.x * gridDim.y;
  int bid = blockIdx.y * gridDim.x + blockIdx.x;
  if ((nwg & 7) == 0) bid = (bid & 7) * (nwg >> 3) + (bid >> 3);
  const int bm = bid % gridDim.y;
  const int bn = bid / gridDim.y;

  const u16* a0 = A + (size_t)(bm * 128 + (t >> 2)) * K + (t & 3) * 8;
  const u16* b0 = B + (size_t)(bn * 128 + (t >> 2)) * K + (t & 3) * 8;
  const size_t rK = (size_t)64 * K;
  u16* as0 = As + t * 8;
  u16* bs0 = Bs + t * 8;

  f32x4 acc[4][4] = {};
  for (int kt = 0; kt < K; kt += 32) {
    GLOAD16(a0 + kt, as0);
    GLOAD16(a0 + rK + kt, as0 + 2048);
    GLOAD16(b0 + kt, bs0);
    GLOAD16(b0 + rK + kt, bs0 + 2048);
    __syncthreads();  // implicit vmcnt(0) drain makes staging visible
    bf16x8 af[4], bfr[4];
#pragma unroll
    for (int i = 0; i < 4; ++i)
      af[i] = *(const bf16x8*)(As + (wr * 64 + i * 16 + lm) * 32 + lg * 8);
#pragma unroll
    for (int j = 0; j < 4; ++j)
      bfr[j] = *(const bf16x8*)(Bs + (wc * 64 + j * 16 + lm) * 32 + lg * 8);
#pragma unroll
    for (int i = 0; i < 4; ++i)
#pragma unroll
      for (int j = 0; j < 4; ++j)
        acc[i][j] = __builtin_amdgcn_mfma_f32_16x16x32_bf16(af[i], bfr[j], acc[i][j], 0, 0, 0);
    __syncthreads();  // protect LDS before next stage
  }
  const int row0 = bm * 128 + wr * 64 + lg * 4;
  const int col0 = bn * 128 + wc * 64 + lm;
  if (c_bf16) {
    u16* C = (u16*)Cout;
#pragma unroll
    for (int i = 0; i < 4; ++i)
#pragma unroll
      for (int r = 0; r < 4; ++r) {
        u16* crow = C + (size_t)(row0 + i * 16 + r) * N + col0;
#pragma unroll
        for (int j = 0; j < 4; ++j) crow[j * 16] = f2bf(acc[i][j][r]);
      }
  } else {
    float* C = (float*)Cout;
#pragma unroll
    for (int i = 0; i < 4; ++i)
#pragma unroll
      for (int r = 0; r < 4; ++r) {
        float* crow = C + (size_t)(row0 + i * 16 + r) * N + col0;
#pragma unroll
        for (int j = 0; j < 4; ++j) crow[j * 16] = acc[i][j][r];
      }
  }
}

// ------- assemble qf = [q_pass | rope(q_rot)] per head, pre-scaled ----------
__global__ void k_mk_qf(const u16* __restrict__ qfull, const float* __restrict__ cosb,
                        const float* __restrict__ sinb, u16* __restrict__ qf) {
  const int s = blockIdx.x, h = blockIdx.y, t = threadIdx.x;
  const u16* src = qfull + (size_t)s * (NH * DQK) + h * DQK;
  u16* dst = qf + ((size_t)h * SEQ + s) * DQK;
  dst[t] = f2bf(bf2f(src[t]) * SCALE);  // t < 128: pass dims
  if (t < 32) {
    float a = bf2f(src[DN + 2 * t]);
    float b = bf2f(src[DN + 2 * t + 1]);
    float c = cosb[(size_t)s * DR + t];
    float sn = sinb[(size_t)s * DR + t];
    dst[DN + t] = f2bf((a * c - b * sn) * SCALE);
    dst[DN + 32 + t] = f2bf((b * c + a * sn) * SCALE);
  }
}

// -------- assemble kf = [k_pass | rope(k_rot)] and v_t[h][d][s] --------------
__global__ void k_mk_kf_v(const u16* __restrict__ kvfull, const float* __restrict__ krot,
                          int krot_stride, const float* __restrict__ cosb,
                          const float* __restrict__ sinb, u16* __restrict__ kf,
                          u16* __restrict__ vt) {
  const int s = blockIdx.x, h = blockIdx.y, t = threadIdx.x;
  const u16* src = kvfull + (size_t)s * (NH * 256) + h * 256;
  u16* kdst = kf + ((size_t)h * SEQ + s) * DQK;
  kdst[t] = src[t];                                  // k_pass
  vt[((size_t)h * DV + t) * SEQ + s] = src[DN + t];  // transposed V
  if (t < 32) {
    float a = krot[(size_t)s * krot_stride + 2 * t];
    float b = krot[(size_t)s * krot_stride + 2 * t + 1];
    float c = cosb[(size_t)s * DR + t];
    float sn = sinb[(size_t)s * DR + t];
    kdst[DN + t] = f2bf(a * c - b * sn);
    kdst[DN + 32 + t] = f2bf(b * c + a * sn);
  }
}

// ---------------- flash attention v3: 1-wave blocks, defer-max softmax -------
// grid: 2048 blocks x 64 thr. Block = (head, 16-row q tile); HW dispatcher
// backfills = dynamic balance; bid&7 pins 2 heads/XCD; longest-first order.
// Softmax: running max m_r (16-lane-group uniform), per-lane partial sum
// l_loc reduced ONCE at the end; max-reduce only when __any(over>8) fires.
__global__ __launch_bounds__(64) void k_attn(
    const u16* __restrict__ qf, const u16* __restrict__ kf, const u16* __restrict__ vt,
    u16* __restrict__ attn_out, const int* __restrict__ cu, int ncu) {
  const int b = blockIdx.x;
  const int lane = threadIdx.x & 63;
  const int lm = lane & 15, lg = lane >> 4;
  const int x = b & 7, rr = b >> 3;   // rr in [0,256)
  const int h = x * 2 + (rr & 1);     // 2 heads per XCD -> K/V L2-resident
  const int qi = 127 - (rr >> 1);     // longest first -> good backfill

  // Q fragments (pre-scaled by 192^-0.5): row = qi*16+lm, k chunk lg*8+c*32
  bf16x8 qfr[6];
  {
    const u16* qp = qf + ((size_t)h * SEQ + (qi * 16 + lm)) * DQK + lg * 8;
#pragma unroll
    for (int c = 0; c < 6; ++c) qfr[c] = *(const bf16x8*)(qp + c * 32);
  }

  const int lo_row = qi * 16;
  int s_lo = 0;
  for (int jj = 0; jj < ncu; ++jj)
    if (cu[jj] <= lo_row) s_lo = cu[jj];
  int qrow[4];
#pragma unroll
  for (int r = 0; r < 4; ++r) qrow[r] = lo_row + lg * 4 + r;
  const int kt_start = s_lo >> 5;
  const int kt_end = (lo_row + 15) >> 5;

  float m_r[4], l_loc[4];
#pragma unroll
  for (int r = 0; r < 4; ++r) { m_r[r] = -3.0e4f; l_loc[r] = 0.f; }
  f32x4 oacc[8] = {};

  __shared__ __align__(16) u16 p_lds[16][32];

  bf16x8 kA[12], kB[12], vv[8];

#define LOADK(kreg, kt)                                                        \
  do {                                                                         \
    const u16* kp_ = kf + ((size_t)h * SEQ + (kt) * 32 + lm) * DQK + lg * 8;   \
    _Pragma("unroll") for (int n0_ = 0; n0_ < 2; ++n0_)                        \
        _Pragma("unroll") for (int c_ = 0; c_ < 6; ++c_)                       \
            kreg[n0_ * 6 + c_] =                                               \
        *(const bf16x8*)(kp_ + (size_t)n0_ * 16 * DQK + c_ * 32);              \
  } while (0)

#define LOADV(kt)                                                              \
  do {                                                                         \
    const u16* vp_ = vt + ((size_t)h * DV + lm) * SEQ + (kt) * 32 + lg * 8;    \
    _Pragma("unroll") for (int nd_ = 0; nd_ < 8; ++nd_)                        \
        vv[nd_] = *(const bf16x8*)(vp_ + (size_t)nd_ * 16 * SEQ);              \
  } while (0)

#define COMPUTE(kreg, kt)                                                      \
  do {                                                                         \
    const int k0_ = (kt) * 32;                                                 \
    f32x4 sc[2] = {};                                                          \
    _Pragma("unroll") for (int n0_ = 0; n0_ < 2; ++n0_)                        \
        _Pragma("unroll") for (int c_ = 0; c_ < 6; ++c_)                       \
            sc[n0_] = __builtin_amdgcn_mfma_f32_16x16x32_bf16(                 \
        qfr[c_], kreg[n0_ * 6 + c_], sc[n0_], 0, 0, 0);                        \
    float s0a[4], s1a[4];                                                      \
    float over = -1e30f;                                                       \
    {                                                                          \
      const int kc0 = k0_ + lm, kc1 = k0_ + 16 + lm;                           \
      _Pragma("unroll") for (int r = 0; r < 4; ++r) {                          \
        s0a[r] = (kc0 >= s_lo && kc0 <= qrow[r]) ? sc[0][r] : -1e30f;          \
        s1a[r] = (kc1 >= s_lo && kc1 <= qrow[r]) ? sc[1][r] : -1e30f;          \
        over = fmaxf(over, fmaxf(s0a[r], s1a[r]) - m_r[r]);                    \
      }                                                                        \
    }                                                                          \
    if (__any(over > 8.0f)) { /* rare rescale path, wave-uniform */            \
      _Pragma("unroll") for (int r = 0; r < 4; ++r) {                          \
        float mx = fmaxf(s0a[r], s1a[r]);                                      \
        _Pragma("unroll") for (int md = 1; md < 16; md <<= 1)                  \
            mx = fmaxf(mx, __shfl_xor(mx, md, 64));                            \
        float mnew = fmaxf(m_r[r], mx);                                        \
        float alpha = __expf(m_r[r] - mnew);                                   \
        m_r[r] = mnew;                                                         \
        l_loc[r] *= alpha;                                                     \
        _Pragma("unroll") for (int nd = 0; nd < 8; ++nd) oacc[nd][r] *= alpha; \
      }                                                                        \
    }                                                                          \
    _Pragma("unroll") for (int r = 0; r < 4; ++r) {                            \
      float p0 = __expf(s0a[r] - m_r[r]);                                      \
      float p1 = __expf(s1a[r] - m_r[r]);                                      \
      l_loc[r] += p0 + p1;                                                     \
      p_lds[lg * 4 + r][lm] = f2bf(p0);                                        \
      p_lds[lg * 4 + r][16 + lm] = f2bf(p1);                                   \
    }                                                                          \
    asm volatile("s_waitcnt lgkmcnt(0)" ::: "memory");                         \
    __builtin_amdgcn_sched_barrier(0);                                         \
    bf16x8 pa = *(const bf16x8*)(&p_lds[lm][lg * 8]);                          \
    _Pragma("unroll") for (int nd = 0; nd < 8; ++nd)                           \
        oacc[nd] =                                                             \
        __builtin_amdgcn_mfma_f32_16x16x32_bf16(pa, vv[nd], oacc[nd], 0, 0, 0);\
  } while (0)

  int kt = kt_start;
  LOADK(kA, kt);
  for (;;) {
    if (kt + 1 <= kt_end) LOADK(kB, kt + 1);
    LOADV(kt);
    COMPUTE(kA, kt);
    ++kt;
    if (kt > kt_end) break;
    if (kt + 1 <= kt_end) LOADK(kA, kt + 1);
    LOADV(kt);
    COMPUTE(kB, kt);
    ++kt;
    if (kt > kt_end) break;
  }
#undef LOADK
#undef LOADV
#undef COMPUTE

#pragma unroll
  for (int r = 0; r < 4; ++r) {
    float lt = l_loc[r];
#pragma unroll
    for (int md = 1; md < 16; md <<= 1) lt += __shfl_xor(lt, md, 64);
    float inv = 1.0f / lt;
#pragma unroll
    for (int nd = 0; nd < 8; ++nd)
      attn_out[(size_t)qrow[r] * (NH * DV) + h * DV + nd * 16 + lm] =
          f2bf(oacc[nd][r] * inv);
  }
}

extern "C" void kernel_launch(void* const* d_in, const int* in_sizes, int n_in,
                              void* d_out, int out_size, void* d_ws, size_t ws_size,
                              hipStream_t stream) {
  const float* hs = (const float*)d_in[0];
  const float* cosb = (const float*)d_in[1];
  const float* sinb = (const float*)d_in[2];
  const float* wq_a = (const float*)d_in[3];
  const float* q_a_ln_w = (const float*)d_in[4];
  const float* wq_b = (const float*)d_in[5];
  const float* wkv_a = (const float*)d_in[6];
  const float* kv_a_ln_w = (const float*)d_in[7];
  const float* wkv_b = (const float*)d_in[8];
  const float* wo = (const float*)d_in[9];
  const int* cu = (const int*)d_in[10];
  const int ncu = in_sizes[10];

  char* ws = (char*)d_ws;
  size_t off = 0;
  auto take = [&](size_t bytes) {
    size_t o = off;
    off += (bytes + 255) & ~(size_t)255;
    return o;
  };
  u16* hs_bf = (u16*)(ws + take((size_t)SEQ * HID * 2));
  u16* wqkva = (u16*)(ws + take((size_t)NKVA * HID * 2));       // [wq_a;wkv_a(pad 640)]
  u16* wqb = (u16*)(ws + take((size_t)(NH * DQK) * QLR * 2));
  u16* wkvb = (u16*)(ws + take((size_t)(NH * 256) * KVLR * 2));
  u16* wo_bf = (u16*)(ws + take((size_t)HID * (NH * DV) * 2));
  float* qkva = (float*)(ws + take((size_t)SEQ * NKVA * 4));    // q_a | kv_c | k_rot | pad
  u16* q_ln = (u16*)(ws + take((size_t)SEQ * QLR * 2));
  u16* kv_ln = (u16*)(ws + take((size_t)SEQ * KVLR * 2));
  u16* qfull = (u16*)(ws + take((size_t)SEQ * NH * DQK * 2));
  u16* kvfull = (u16*)(ws + take((size_t)SEQ * NH * 256 * 2));
  u16* qf = (u16*)(ws + take((size_t)NH * SEQ * DQK * 2));
  u16* kf = (u16*)(ws + take((size_t)NH * SEQ * DQK * 2));
  u16* vt = (u16*)(ws + take((size_t)NH * DV * SEQ * 2));
  u16* attn = (u16*)(ws + take((size_t)SEQ * NH * DV * 2));
  if (off > ws_size) return;

  auto blocks4 = [](long n) {
    long b = (n / 4 + 255) / 256;
    return (int)(b > 4096 ? 4096 : b);
  };

  // converts (f32 -> bf16), wkv_a zero-padded 576 -> 640 rows
  k_convert<<<blocks4((long)SEQ * HID), 256, 0, stream>>>(hs, hs_bf, (long)SEQ * HID, (long)SEQ * HID);
  k_convert<<<blocks4((long)QLR * HID), 256, 0, stream>>>(wq_a, wqkva, (long)QLR * HID, (long)QLR * HID);
  k_convert<<<blocks4((long)640 * HID), 256, 0, stream>>>(wkv_a, wqkva + (size_t)QLR * HID,
                                                          (long)(KVLR + DR) * HID, (long)640 * HID);
  k_convert<<<blocks4((long)NH * DQK * QLR), 256, 0, stream>>>(wq_b, wqb, (long)NH * DQK * QLR,
                                                               (long)NH * DQK * QLR);
  k_convert<<<blocks4((long)NH * 256 * KVLR), 256, 0, stream>>>(wkv_b, wkvb, (long)NH * 256 * KVLR,
                                                                (long)NH * 256 * KVLR);
  k_convert<<<blocks4((long)HID * NH * DV), 256, 0, stream>>>(wo, wo_bf, (long)HID * NH * DV,
                                                              (long)HID * NH * DV);

  // fused low-rank down-proj: [q_a | ckv] = hs @ [wq_a;wkv_a]^T
  dim3 g1(NKVA / 128, SEQ / 128);
  k_gemm_nt<<<g1, 256, 0, stream>>>(hs_bf, wqkva, qkva, SEQ, NKVA, HID, 0);

  k_rmsnorm<<<SEQ, 256, 0, stream>>>(qkva, q_a_ln_w, q_ln, NKVA, QLR, 1.0f / QLR);
  k_rmsnorm<<<SEQ, 256, 0, stream>>>(qkva + QLR, kv_a_ln_w, kv_ln, NKVA, KVLR, 1.0f / KVLR);

  dim3 g2(NH * DQK / 128, SEQ / 128);
  k_gemm_nt<<<g2, 256, 0, stream>>>(q_ln, wqb, qfull, SEQ, NH * DQK, QLR, 1);
  dim3 g3(NH * 256 / 128, SEQ / 128);
  k_gemm_nt<<<g3, 256, 0, stream>>>(kv_ln, wkvb, kvfull, SEQ, NH * 256, KVLR, 1);

  k_mk_qf<<<dim3(SEQ, NH), 128, 0, stream>>>(qfull, cosb, sinb, qf);
  k_mk_kf_v<<<dim3(SEQ, NH), 128, 0, stream>>>(kvfull, qkva + (QLR + KVLR), NKVA, cosb, sinb, kf, vt);

  k_attn<<<2048, 64, 0, stream>>>(qf, kf, vt, attn, cu, ncu);

  dim3 g4(HID / 128, SEQ / 128);
  k_gemm_nt<<<g4, 256, 0, stream>>>(attn, wo_bf, d_out, SEQ, HID, NH * DV, 0);
}